// Round 5
// baseline (320.896 us; speedup 1.0000x reference)
//
#include <hip/hip_runtime.h>
#include <stdint.h>

typedef unsigned short ushort_t;
typedef __attribute__((ext_vector_type(8))) short short8;
typedef __attribute__((ext_vector_type(4))) float floatx4;

// ---------- helpers ----------

__device__ __forceinline__ ushort_t f2bf(float f) {
  unsigned int u = __builtin_bit_cast(unsigned int, f);
  u += 0x7fffu + ((u >> 16) & 1u);   // round-to-nearest-even
  return (ushort_t)(u >> 16);
}

__device__ __forceinline__ void gld16(const void* g, void* l) {
  __builtin_amdgcn_global_load_lds(
      (__attribute__((address_space(1))) void*)(void*)(g),
      (__attribute__((address_space(3))) void*)(l), 16, 0, 0);
}

// ---------- merged f32 -> bf16 cast ----------

__global__ __launch_bounds__(256)
void cast_all_kernel(const float* __restrict__ h, const float* __restrict__ wq,
                     const float* __restrict__ wk, const float* __restrict__ wv,
                     const float* __restrict__ wo,
                     ushort_t* __restrict__ h_bf, ushort_t* __restrict__ wqkv_bf,
                     ushort_t* __restrict__ wo_bf, float qscale) {
  long i = (long)blockIdx.x * 256 + threadIdx.x;
  const float4* src; ushort4* dst; float sc = 1.0f;
  if (i < 2097152L)       { src = (const float4*)h  + i;             dst = (ushort4*)h_bf + i; }
  else if (i < 3145728L)  { src = (const float4*)wq + (i - 2097152); dst = (ushort4*)wqkv_bf + (i - 2097152); sc = qscale; }
  else if (i < 3407872L)  { src = (const float4*)wk + (i - 3145728); dst = (ushort4*)wqkv_bf + (i - 3145728) + 1048576; }
  else if (i < 3670016L)  { src = (const float4*)wv + (i - 3407872); dst = (ushort4*)wqkv_bf + (i - 3407872) + 1310720; }
  else                    { src = (const float4*)wo + (i - 3670016); dst = (ushort4*)wo_bf + (i - 3670016); }
  float4 v = *src; ushort4 o;
  o.x = f2bf(v.x * sc); o.y = f2bf(v.y * sc);
  o.z = f2bf(v.z * sc); o.w = f2bf(v.w * sc);
  *dst = o;
}

// ---------- GEMM: C[M,N] = A[M,K] @ B[N,K]^T  (m97 structure, known-good) ----

template <int OM>   // 0: bf16 out, 1: f32 out
__global__ __launch_bounds__(256)
void gemm_bt(const ushort_t* __restrict__ A, const ushort_t* __restrict__ B,
             void* __restrict__ Cp, int M, int N, int K) {
  __shared__ ushort_t As[128 * 32];
  __shared__ ushort_t Bs[128 * 32];
  const int tid  = threadIdx.x;
  const int wave = tid >> 6, lane = tid & 63;
  const int quad = lane >> 4, l16 = lane & 15;
  const int wm = (wave >> 1) * 64, wn = (wave & 1) * 64;
  const int bm = blockIdx.x * 128, bn = blockIdx.y * 128;
  const int srow = lane >> 2, scc = lane & 3;

  floatx4 acc[4][4] = {};

  for (int k0 = 0; k0 < K; k0 += 32) {
#pragma unroll
    for (int r = 0; r < 2; ++r) {
      int c   = wave * 2 + r;
      int row = c * 16 + srow;
      int g   = scc ^ ((row >> 1) & 3);
      gld16(A + (long)(bm + row) * K + k0 + g * 8, As + c * 512 + lane * 8);
      gld16(B + (long)(bn + row) * K + k0 + g * 8, Bs + c * 512 + lane * 8);
    }
    __syncthreads();

    short8 af[4], bf[4];
#pragma unroll
    for (int i = 0; i < 4; ++i) {
      int m = wm + i * 16 + l16;
      af[i] = *(const short8*)(As + m * 32 + ((quad ^ ((m >> 1) & 3)) * 8));
      int n = wn + i * 16 + l16;
      bf[i] = *(const short8*)(Bs + n * 32 + ((quad ^ ((n >> 1) & 3)) * 8));
    }
#pragma unroll
    for (int i = 0; i < 4; ++i)
#pragma unroll
      for (int j = 0; j < 4; ++j)
        acc[i][j] = __builtin_amdgcn_mfma_f32_16x16x32_bf16(af[i], bf[j], acc[i][j], 0, 0, 0);
    __syncthreads();
  }

#pragma unroll
  for (int i = 0; i < 4; ++i)
#pragma unroll
    for (int j = 0; j < 4; ++j)
#pragma unroll
      for (int r = 0; r < 4; ++r) {
        int row = bm + wm + i * 16 + quad * 4 + r;
        int col = bn + wn + j * 16 + l16;
        if (OM == 0) ((ushort_t*)Cp)[(long)row * N + col] = f2bf(acc[i][j][r]);
        else         ((float*)Cp)[(long)row * N + col]    = acc[i][j][r];
      }
}

// ---------- V transpose pre-pass: Vtg[b][kvh][hd][l] ----------

__global__ __launch_bounds__(256)
void transpose_v(const ushort_t* __restrict__ QKV, ushort_t* __restrict__ Vtg) {
  __shared__ ushort_t t[64 * 72];
  const int tid = threadIdx.x;
  const int b = blockIdx.z, kvh = blockIdx.y, l0 = blockIdx.x * 64;
#pragma unroll
  for (int r = 0; r < 2; ++r) {
    int idx = tid + r * 256;
    int row = idx >> 3, sub = idx & 7;
    short8 v = *(const short8*)(QKV + (long)(b * 2048 + l0 + row) * 3072 + 2560 + kvh * 64 + sub * 8);
    *(short8*)(t + row * 72 + sub * 8) = v;
  }
  __syncthreads();
#pragma unroll
  for (int r = 0; r < 2; ++r) {
    int idx = tid + r * 256;
    int hd = idx >> 3, sub = idx & 7;
    short8 o;
#pragma unroll
    for (int e = 0; e < 8; ++e) o[e] = (short)t[(sub * 8 + e) * 72 + hd];
    *(short8*)(Vtg + (long)((b * 8 + kvh) * 64 + hd) * 2048 + l0 + sub * 8) = o;
  }
}

// ---------- fused flash attention, S^T form, q-tile 128 (32 q/wave) ----------
// 4096 waves = 4/SIMD for latency hiding; LDS 40KB -> 4 blocks/CU. Pt is a
// half-l (32-col) per-iter buffer; exp/pack of half B overlaps PV MFMAs of
// half A in the matrix pipe. Row-sums via ones-column MFMA (C-layout aligned).

__global__ __launch_bounds__(256, 4)
void attn_kernel(const ushort_t* __restrict__ QKV, const ushort_t* __restrict__ Vtg,
                 ushort_t* __restrict__ AO) {
  __shared__ ushort_t Ks[2][64 * 64];   // 16 KB dbuf [l][hd]
  __shared__ ushort_t Vt[2][64 * 64];   // 16 KB dbuf [hd][l]
  __shared__ ushort_t Pt[128 * 32];     // 8 KB [q][l-half], per-wave rows, reused per half

  const int tid  = threadIdx.x;
  const int wave = tid >> 6, lane = tid & 63;
  const int quad = lane >> 4, l16 = lane & 15;
  const int b = blockIdx.z, h = blockIdx.y;
  const int q0 = blockIdx.x * 128;
  const int kvh = h >> 2;
  const long tok0 = (long)b * 2048 + q0;

  // Q B-frags, loop-invariant (wq carries 0.125*log2(e) -> exp2 domain)
  short8 qf[2][2];
#pragma unroll
  for (int kb = 0; kb < 2; ++kb)
#pragma unroll
    for (int j = 0; j < 2; ++j)
      qf[kb][j] = *(const short8*)(QKV + (tok0 + wave * 32 + j * 16 + l16) * 3072
                                   + h * 64 + kb * 32 + quad * 8);

  floatx4 oacc[2][4] = {};
  floatx4 osum[2] = {};

  short8 bones;
#pragma unroll
  for (int e = 0; e < 8; ++e) bones[e] = (short)0x3F80;   // bf16 1.0

  const int lr = lane >> 3, sub = lane & 7;
  const int g = sub ^ lr;
  const ushort_t* Kbase = QKV + (long)b * 2048 * 3072 + 2048 + kvh * 64;
  const ushort_t* Vbase = Vtg + (long)(b * 8 + kvh) * 64 * 2048;

  auto stage = [&](int bf_, int l0) {
#pragma unroll
    for (int r = 0; r < 2; ++r) {
      int c = wave * 2 + r;
      int row = c * 8 + lr;
      gld16(Kbase + (long)(l0 + row) * 3072 + g * 8, Ks[bf_] + c * 512 + lane * 8);
      gld16(Vbase + (long)row * 2048 + l0 + g * 8, Vt[bf_] + c * 512 + lane * 8);
    }
  };

  stage(0, 0);

  for (int it = 0; it < 32; ++it) {
    __syncthreads();
    if (it + 1 < 32) stage((it + 1) & 1, (it + 1) * 64);
    const ushort_t* Kc = Ks[it & 1];
    const ushort_t* Vc = Vt[it & 1];

    // S^T = K . Q^T : 64 l-rows x 32 q-cols per wave
    floatx4 s[4][2] = {};
#pragma unroll
    for (int kb = 0; kb < 2; ++kb) {
      short8 kf[4];
#pragma unroll
      for (int i = 0; i < 4; ++i)
        kf[i] = *(const short8*)(Kc + (i * 16 + l16) * 64 + (((kb * 4 + quad) ^ (l16 & 7)) * 8));
#pragma unroll
      for (int i = 0; i < 4; ++i)
#pragma unroll
        for (int j = 0; j < 2; ++j)
          s[i][j] = __builtin_amdgcn_mfma_f32_16x16x32_bf16(kf[i], qf[kb][j], s[i][j], 0, 0, 0);
    }

    // process l-halves: exp/pack half -> Pt -> PV MFMAs of that half.
    // Half B's exp issues while half A's PV occupies the matrix pipe.
#pragma unroll
    for (int hh = 0; hh < 2; ++hh) {
      // exp + truncation-pack (v_perm) for l in [hh*32, hh*32+32)
#pragma unroll
      for (int ii = 0; ii < 2; ++ii) {
        int i = hh * 2 + ii;
#pragma unroll
        for (int j = 0; j < 2; ++j) {
          float p0 = __builtin_amdgcn_exp2f(s[i][j][0]);
          float p1 = __builtin_amdgcn_exp2f(s[i][j][1]);
          float p2 = __builtin_amdgcn_exp2f(s[i][j][2]);
          float p3 = __builtin_amdgcn_exp2f(s[i][j][3]);
          uint2 w;
          w.x = __builtin_amdgcn_perm(__builtin_bit_cast(unsigned int, p1),
                                      __builtin_bit_cast(unsigned int, p0), 0x07060302u);
          w.y = __builtin_amdgcn_perm(__builtin_bit_cast(unsigned int, p3),
                                      __builtin_bit_cast(unsigned int, p2), 0x07060302u);
          int q = wave * 32 + j * 16 + l16;
          int c = ii * 2 + (quad >> 1);           // 16B chunk within 64B row
          int idx = q * 32 + ((c ^ (l16 & 3)) * 8) + (quad & 1) * 4;
          *(uint2*)(Pt + idx) = w;
        }
      }
      // O += P_half . V_half ; row-sums += P_half . ones   (k = l-half)
      short8 pf[2], vf[4];
#pragma unroll
      for (int im = 0; im < 2; ++im)
        pf[im] = *(const short8*)(Pt + (wave * 32 + im * 16 + l16) * 32
                                  + ((quad ^ (l16 & 3)) * 8));
#pragma unroll
      for (int n = 0; n < 4; ++n)
        vf[n] = *(const short8*)(Vc + (n * 16 + l16) * 64
                                 + (((hh * 4 + quad) ^ (l16 & 7)) * 8));
#pragma unroll
      for (int im = 0; im < 2; ++im) {
#pragma unroll
        for (int n = 0; n < 4; ++n)
          oacc[im][n] = __builtin_amdgcn_mfma_f32_16x16x32_bf16(pf[im], vf[n], oacc[im][n], 0, 0, 0);
        osum[im] = __builtin_amdgcn_mfma_f32_16x16x32_bf16(pf[im], bones, osum[im], 0, 0, 0);
      }
    }
  }

  // epilogue: osum[im][r] is the softmax denominator, same layout as oacc.
#pragma unroll
  for (int im = 0; im < 2; ++im) {
    floatx4 inv;
#pragma unroll
    for (int r = 0; r < 4; ++r) inv[r] = 1.0f / osum[im][r];
#pragma unroll
    for (int n = 0; n < 4; ++n)
#pragma unroll
      for (int r = 0; r < 4; ++r) {
        long t = tok0 + wave * 32 + im * 16 + quad * 4 + r;
        AO[t * 2048 + h * 64 + n * 16 + l16] = f2bf(oacc[im][n][r] * inv[r]);
      }
  }
}

// ---------- launch ----------

extern "C" void kernel_launch(void* const* d_in, const int* in_sizes, int n_in,
                              void* d_out, int out_size, void* d_ws, size_t ws_size,
                              hipStream_t stream) {
  const float* h  = (const float*)d_in[0];
  const float* wq = (const float*)d_in[1];
  const float* wk = (const float*)d_in[2];
  const float* wv = (const float*)d_in[3];
  const float* wo = (const float*)d_in[4];
  float* out = (float*)d_out;

  const int BS = 4096, D = 2048, KV = 512, NQKV = 3072;

  ushort_t* h_bf    = (ushort_t*)d_ws;
  ushort_t* wqkv_bf = h_bf + (long)BS * D;
  ushort_t* wo_bf   = wqkv_bf + (long)NQKV * D;
  ushort_t* QKV     = wo_bf + (long)D * D;
  ushort_t* Vtg     = QKV + (long)BS * NQKV;
  ushort_t* AO      = h_bf;   // reuse: h_bf dead after QKV gemm

  const float qscale = 0.125f * 1.44269504088896f;  // 1/sqrt(64) * log2(e)

  cast_all_kernel<<<4718592 / 256, 256, 0, stream>>>(h, wq, wk, wv, wo,
                                                     h_bf, wqkv_bf, wo_bf, qscale);

  gemm_bt<0><<<dim3(BS / 128, NQKV / 128), 256, 0, stream>>>(h_bf, wqkv_bf, QKV, BS, NQKV, D);

  transpose_v<<<dim3(32, 8, 2), 256, 0, stream>>>(QKV, Vtg);

  attn_kernel<<<dim3(2048 / 128, 32, 2), 256, 0, stream>>>(QKV, Vtg, AO);

  gemm_bt<1><<<dim3(BS / 128, D / 128), 256, 0, stream>>>(AO, wo_bf, out, BS, D, D);
}

// Round 6
// 311.588 us; speedup vs baseline: 1.0299x; 1.0299x over previous
//
#include <hip/hip_runtime.h>
#include <stdint.h>

typedef unsigned short ushort_t;
typedef __attribute__((ext_vector_type(8))) short short8;
typedef __attribute__((ext_vector_type(4))) float floatx4;

// ---------- helpers ----------

__device__ __forceinline__ ushort_t f2bf(float f) {
  unsigned int u = __builtin_bit_cast(unsigned int, f);
  u += 0x7fffu + ((u >> 16) & 1u);   // round-to-nearest-even
  return (ushort_t)(u >> 16);
}

__device__ __forceinline__ void gld16(const void* g, void* l) {
  __builtin_amdgcn_global_load_lds(
      (__attribute__((address_space(1))) void*)(void*)(g),
      (__attribute__((address_space(3))) void*)(l), 16, 0, 0);
}

// ---------- merged f32 -> bf16 cast ----------

__global__ __launch_bounds__(256)
void cast_all_kernel(const float* __restrict__ h, const float* __restrict__ wq,
                     const float* __restrict__ wk, const float* __restrict__ wv,
                     const float* __restrict__ wo,
                     ushort_t* __restrict__ h_bf, ushort_t* __restrict__ wqkv_bf,
                     ushort_t* __restrict__ wo_bf, float qscale) {
  long i = (long)blockIdx.x * 256 + threadIdx.x;
  const float4* src; ushort4* dst; float sc = 1.0f;
  if (i < 2097152L)       { src = (const float4*)h  + i;             dst = (ushort4*)h_bf + i; }
  else if (i < 3145728L)  { src = (const float4*)wq + (i - 2097152); dst = (ushort4*)wqkv_bf + (i - 2097152); sc = qscale; }
  else if (i < 3407872L)  { src = (const float4*)wk + (i - 3145728); dst = (ushort4*)wqkv_bf + (i - 3145728) + 1048576; }
  else if (i < 3670016L)  { src = (const float4*)wv + (i - 3407872); dst = (ushort4*)wqkv_bf + (i - 3407872) + 1310720; }
  else                    { src = (const float4*)wo + (i - 3670016); dst = (ushort4*)wo_bf + (i - 3670016); }
  float4 v = *src; ushort4 o;
  o.x = f2bf(v.x * sc); o.y = f2bf(v.y * sc);
  o.z = f2bf(v.z * sc); o.w = f2bf(v.w * sc);
  *dst = o;
}

// ---------- GEMM: C[M,N] = A[M,K] @ B[N,K]^T  (m97 structure, known-good) ----

template <int OM>   // 0: bf16 out, 1: f32 out
__global__ __launch_bounds__(256)
void gemm_bt(const ushort_t* __restrict__ A, const ushort_t* __restrict__ B,
             void* __restrict__ Cp, int M, int N, int K) {
  __shared__ ushort_t As[128 * 32];
  __shared__ ushort_t Bs[128 * 32];
  const int tid  = threadIdx.x;
  const int wave = tid >> 6, lane = tid & 63;
  const int quad = lane >> 4, l16 = lane & 15;
  const int wm = (wave >> 1) * 64, wn = (wave & 1) * 64;
  const int bm = blockIdx.x * 128, bn = blockIdx.y * 128;
  const int srow = lane >> 2, scc = lane & 3;

  floatx4 acc[4][4] = {};

  for (int k0 = 0; k0 < K; k0 += 32) {
#pragma unroll
    for (int r = 0; r < 2; ++r) {
      int c   = wave * 2 + r;
      int row = c * 16 + srow;
      int g   = scc ^ ((row >> 1) & 3);
      gld16(A + (long)(bm + row) * K + k0 + g * 8, As + c * 512 + lane * 8);
      gld16(B + (long)(bn + row) * K + k0 + g * 8, Bs + c * 512 + lane * 8);
    }
    __syncthreads();

    short8 af[4], bf[4];
#pragma unroll
    for (int i = 0; i < 4; ++i) {
      int m = wm + i * 16 + l16;
      af[i] = *(const short8*)(As + m * 32 + ((quad ^ ((m >> 1) & 3)) * 8));
      int n = wn + i * 16 + l16;
      bf[i] = *(const short8*)(Bs + n * 32 + ((quad ^ ((n >> 1) & 3)) * 8));
    }
#pragma unroll
    for (int i = 0; i < 4; ++i)
#pragma unroll
      for (int j = 0; j < 4; ++j)
        acc[i][j] = __builtin_amdgcn_mfma_f32_16x16x32_bf16(af[i], bf[j], acc[i][j], 0, 0, 0);
    __syncthreads();
  }

#pragma unroll
  for (int i = 0; i < 4; ++i)
#pragma unroll
    for (int j = 0; j < 4; ++j)
#pragma unroll
      for (int r = 0; r < 4; ++r) {
        int row = bm + wm + i * 16 + quad * 4 + r;
        int col = bn + wn + j * 16 + l16;
        if (OM == 0) ((ushort_t*)Cp)[(long)row * N + col] = f2bf(acc[i][j][r]);
        else         ((float*)Cp)[(long)row * N + col]    = acc[i][j][r];
      }
}

// ---------- V transpose pre-pass: Vtg[b][kvh][hd][l] ----------

__global__ __launch_bounds__(256)
void transpose_v(const ushort_t* __restrict__ QKV, ushort_t* __restrict__ Vtg) {
  __shared__ ushort_t t[64 * 72];
  const int tid = threadIdx.x;
  const int b = blockIdx.z, kvh = blockIdx.y, l0 = blockIdx.x * 64;
#pragma unroll
  for (int r = 0; r < 2; ++r) {
    int idx = tid + r * 256;
    int row = idx >> 3, sub = idx & 7;
    short8 v = *(const short8*)(QKV + (long)(b * 2048 + l0 + row) * 3072 + 2560 + kvh * 64 + sub * 8);
    *(short8*)(t + row * 72 + sub * 8) = v;
  }
  __syncthreads();
#pragma unroll
  for (int r = 0; r < 2; ++r) {
    int idx = tid + r * 256;
    int hd = idx >> 3, sub = idx & 7;
    short8 o;
#pragma unroll
    for (int e = 0; e < 8; ++e) o[e] = (short)t[(sub * 8 + e) * 72 + hd];
    *(short8*)(Vtg + (long)((b * 8 + kvh) * 64 + hd) * 2048 + l0 + sub * 8) = o;
  }
}

// ---------- fused flash attention, S^T form, q-tile 256 (64 q/wave) ----------
// R4 structure. Pt row stride = 68 elements (136B): bank base rotates 2q mod 32
// words per row, making the pf ds_read_b128 2-way max (free) instead of the
// 8-lanes-per-chunk pileup at stride 64. Data mapping (chunk ^ (row&7))
// unchanged — only the stride. Ks/Vt can't be padded (global_load_lds dense
// lane*16 destination requirement).

__global__ __launch_bounds__(256, 2)
void attn_kernel(const ushort_t* __restrict__ QKV, const ushort_t* __restrict__ Vtg,
                 ushort_t* __restrict__ AO) {
  __shared__ ushort_t Ks[2][64 * 64];   // 16 KB dbuf [l][hd]
  __shared__ ushort_t Vt[2][64 * 64];   // 16 KB dbuf [hd][l]
  __shared__ ushort_t Pt[256 * 68];     // 34 KB [q][l], stride 68, per-wave rows

  const int tid  = threadIdx.x;
  const int wave = tid >> 6, lane = tid & 63;
  const int quad = lane >> 4, l16 = lane & 15;
  const int b = blockIdx.z, h = blockIdx.y;
  const int q0 = blockIdx.x * 256;
  const int kvh = h >> 2;
  const long tok0 = (long)b * 2048 + q0;

  // Q B-frags, loop-invariant (wq carries 0.125*log2(e) -> exp2 domain)
  short8 qf[2][4];
#pragma unroll
  for (int kb = 0; kb < 2; ++kb)
#pragma unroll
    for (int j = 0; j < 4; ++j)
      qf[kb][j] = *(const short8*)(QKV + (tok0 + wave * 64 + j * 16 + l16) * 3072
                                   + h * 64 + kb * 32 + quad * 8);

  floatx4 oacc[4][4] = {};
  floatx4 osum[4] = {};                 // ones-column row-sum accumulators

  short8 bones;
#pragma unroll
  for (int e = 0; e < 8; ++e) bones[e] = (short)0x3F80;   // bf16 1.0

  const int lr = lane >> 3, sub = lane & 7;
  const int g = sub ^ lr;
  const ushort_t* Kbase = QKV + (long)b * 2048 * 3072 + 2048 + kvh * 64;
  const ushort_t* Vbase = Vtg + (long)(b * 8 + kvh) * 64 * 2048;

  auto stage = [&](int bf_, int l0) {
#pragma unroll
    for (int r = 0; r < 2; ++r) {
      int c = wave * 2 + r;
      int row = c * 8 + lr;
      gld16(Kbase + (long)(l0 + row) * 3072 + g * 8, Ks[bf_] + c * 512 + lane * 8);
      gld16(Vbase + (long)row * 2048 + l0 + g * 8, Vt[bf_] + c * 512 + lane * 8);
    }
  };

  stage(0, 0);

  for (int it = 0; it < 32; ++it) {
    __syncthreads();
    if (it + 1 < 32) stage((it + 1) & 1, (it + 1) * 64);
    const ushort_t* Kc = Ks[it & 1];
    const ushort_t* Vc = Vt[it & 1];

    // S^T = K . Q^T : 64 l-rows x 64 q-cols per wave
    floatx4 s[4][4] = {};
#pragma unroll
    for (int kb = 0; kb < 2; ++kb) {
      short8 kf[4];
#pragma unroll
      for (int i = 0; i < 4; ++i)
        kf[i] = *(const short8*)(Kc + (i * 16 + l16) * 64 + (((kb * 4 + quad) ^ (l16 & 7)) * 8));
#pragma unroll
      for (int i = 0; i < 4; ++i)
#pragma unroll
        for (int j = 0; j < 4; ++j)
          s[i][j] = __builtin_amdgcn_mfma_f32_16x16x32_bf16(kf[i], qf[kb][j], s[i][j], 0, 0, 0);
    }

    // p = 2^s, truncation-pack via v_perm, b64 Pt writes
#pragma unroll
    for (int i = 0; i < 4; ++i)
#pragma unroll
      for (int j = 0; j < 4; ++j) {
        float p0 = __builtin_amdgcn_exp2f(s[i][j][0]);
        float p1 = __builtin_amdgcn_exp2f(s[i][j][1]);
        float p2 = __builtin_amdgcn_exp2f(s[i][j][2]);
        float p3 = __builtin_amdgcn_exp2f(s[i][j][3]);
        uint2 w;
        w.x = __builtin_amdgcn_perm(__builtin_bit_cast(unsigned int, p1),
                                    __builtin_bit_cast(unsigned int, p0), 0x07060302u);
        w.y = __builtin_amdgcn_perm(__builtin_bit_cast(unsigned int, p3),
                                    __builtin_bit_cast(unsigned int, p2), 0x07060302u);
        int q = wave * 64 + j * 16 + l16;
        int idx = q * 68 + (((i * 2 + (quad >> 1)) ^ (l16 & 7)) * 8) + (quad & 1) * 4;
        *(uint2*)(Pt + idx) = w;
      }
    // no barrier: each wave reads only Pt rows it wrote

    // O += P . V ; row-sums += P . ones
#pragma unroll
    for (int kb = 0; kb < 2; ++kb) {
      short8 pf[4], vf[4];
#pragma unroll
      for (int im = 0; im < 4; ++im)
        pf[im] = *(const short8*)(Pt + (wave * 64 + im * 16 + l16) * 68
                                  + (((kb * 4 + quad) ^ (l16 & 7)) * 8));
#pragma unroll
      for (int n = 0; n < 4; ++n)
        vf[n] = *(const short8*)(Vc + (n * 16 + l16) * 64
                                 + (((kb * 4 + quad) ^ (l16 & 7)) * 8));
#pragma unroll
      for (int im = 0; im < 4; ++im) {
#pragma unroll
        for (int n = 0; n < 4; ++n)
          oacc[im][n] = __builtin_amdgcn_mfma_f32_16x16x32_bf16(pf[im], vf[n], oacc[im][n], 0, 0, 0);
        osum[im] = __builtin_amdgcn_mfma_f32_16x16x32_bf16(pf[im], bones, osum[im], 0, 0, 0);
      }
    }
  }

  // epilogue: osum[im][r] is the softmax denominator, same layout as oacc.
#pragma unroll
  for (int im = 0; im < 4; ++im) {
    floatx4 inv;
#pragma unroll
    for (int r = 0; r < 4; ++r) inv[r] = 1.0f / osum[im][r];
#pragma unroll
    for (int n = 0; n < 4; ++n)
#pragma unroll
      for (int r = 0; r < 4; ++r) {
        long t = tok0 + wave * 64 + im * 16 + quad * 4 + r;
        AO[t * 2048 + h * 64 + n * 16 + l16] = f2bf(oacc[im][n][r] * inv[r]);
      }
  }
}

// ---------- launch ----------

extern "C" void kernel_launch(void* const* d_in, const int* in_sizes, int n_in,
                              void* d_out, int out_size, void* d_ws, size_t ws_size,
                              hipStream_t stream) {
  const float* h  = (const float*)d_in[0];
  const float* wq = (const float*)d_in[1];
  const float* wk = (const float*)d_in[2];
  const float* wv = (const float*)d_in[3];
  const float* wo = (const float*)d_in[4];
  float* out = (float*)d_out;

  const int BS = 4096, D = 2048, KV = 512, NQKV = 3072;

  ushort_t* h_bf    = (ushort_t*)d_ws;
  ushort_t* wqkv_bf = h_bf + (long)BS * D;
  ushort_t* wo_bf   = wqkv_bf + (long)NQKV * D;
  ushort_t* QKV     = wo_bf + (long)D * D;
  ushort_t* Vtg     = QKV + (long)BS * NQKV;
  ushort_t* AO      = h_bf;   // reuse: h_bf dead after QKV gemm

  const float qscale = 0.125f * 1.44269504088896f;  // 1/sqrt(64) * log2(e)

  cast_all_kernel<<<4718592 / 256, 256, 0, stream>>>(h, wq, wk, wv, wo,
                                                     h_bf, wqkv_bf, wo_bf, qscale);

  gemm_bt<0><<<dim3(BS / 128, NQKV / 128), 256, 0, stream>>>(h_bf, wqkv_bf, QKV, BS, NQKV, D);

  transpose_v<<<dim3(32, 8, 2), 256, 0, stream>>>(QKV, Vtg);

  attn_kernel<<<dim3(2048 / 256, 32, 2), 256, 0, stream>>>(QKV, Vtg, AO);

  gemm_bt<1><<<dim3(BS / 128, D / 128), 256, 0, stream>>>(AO, wo_bf, out, BS, D, D);
}

// Round 7
// 292.438 us; speedup vs baseline: 1.0973x; 1.0655x over previous
//
#include <hip/hip_runtime.h>
#include <stdint.h>

typedef unsigned short ushort_t;
typedef __attribute__((ext_vector_type(8))) short short8;
typedef __attribute__((ext_vector_type(4))) float floatx4;

// ---------- helpers ----------

__device__ __forceinline__ ushort_t f2bf(float f) {
  unsigned int u = __builtin_bit_cast(unsigned int, f);
  u += 0x7fffu + ((u >> 16) & 1u);   // round-to-nearest-even
  return (ushort_t)(u >> 16);
}

__device__ __forceinline__ void gld16(const void* g, void* l) {
  __builtin_amdgcn_global_load_lds(
      (__attribute__((address_space(1))) void*)(void*)(g),
      (__attribute__((address_space(3))) void*)(l), 16, 0, 0);
}

// ---------- merged f32 -> bf16 cast ----------

__global__ __launch_bounds__(256)
void cast_all_kernel(const float* __restrict__ h, const float* __restrict__ wq,
                     const float* __restrict__ wk, const float* __restrict__ wv,
                     const float* __restrict__ wo,
                     ushort_t* __restrict__ h_bf, ushort_t* __restrict__ wqkv_bf,
                     ushort_t* __restrict__ wo_bf, float qscale) {
  long i = (long)blockIdx.x * 256 + threadIdx.x;
  const float4* src; ushort4* dst; float sc = 1.0f;
  if (i < 2097152L)       { src = (const float4*)h  + i;             dst = (ushort4*)h_bf + i; }
  else if (i < 3145728L)  { src = (const float4*)wq + (i - 2097152); dst = (ushort4*)wqkv_bf + (i - 2097152); sc = qscale; }
  else if (i < 3407872L)  { src = (const float4*)wk + (i - 3145728); dst = (ushort4*)wqkv_bf + (i - 3145728) + 1048576; }
  else if (i < 3670016L)  { src = (const float4*)wv + (i - 3407872); dst = (ushort4*)wqkv_bf + (i - 3407872) + 1310720; }
  else                    { src = (const float4*)wo + (i - 3670016); dst = (ushort4*)wo_bf + (i - 3670016); }
  float4 v = *src; ushort4 o;
  o.x = f2bf(v.x * sc); o.y = f2bf(v.y * sc);
  o.z = f2bf(v.z * sc); o.w = f2bf(v.w * sc);
  *dst = o;
}

// ---------- GEMM: C[M,N] = A[M,K] @ B[N,K]^T, BK=64 ----------
// m97 structure with BK=64: 2x MFMA per barrier (amortizes the vmcnt(0)
// barrier-drain stall), LDS 32 KB (still 3 blocks/CU — dodges the m132
// 64 KB occupancy cliff). 16 chunks of 1KB per matrix; chunk c = rows
// [8c,8c+8), row = 128B = 8 sub-chunks, swizzle sub ^ (row&7).

template <int OM>   // 0: bf16 out, 1: f32 out
__global__ __launch_bounds__(256)
void gemm_bt(const ushort_t* __restrict__ A, const ushort_t* __restrict__ B,
             void* __restrict__ Cp, int M, int N, int K) {
  __shared__ ushort_t As[128 * 64];   // 16 KB
  __shared__ ushort_t Bs[128 * 64];   // 16 KB
  const int tid  = threadIdx.x;
  const int wave = tid >> 6, lane = tid & 63;
  const int quad = lane >> 4, l16 = lane & 15;
  const int wm = (wave >> 1) * 64, wn = (wave & 1) * 64;
  const int bm = blockIdx.x * 128, bn = blockIdx.y * 128;
  const int srow8 = lane >> 3, sub = lane & 7;
  const int g = sub ^ srow8;          // row&7 == srow8 for all chunks

  floatx4 acc[4][4] = {};

  for (int k0 = 0; k0 < K; k0 += 64) {
#pragma unroll
    for (int r = 0; r < 4; ++r) {
      int c   = wave * 4 + r;          // 16 chunks per matrix
      int row = c * 8 + srow8;
      gld16(A + (long)(bm + row) * K + k0 + g * 8, As + c * 512 + lane * 8);
      gld16(B + (long)(bn + row) * K + k0 + g * 8, Bs + c * 512 + lane * 8);
    }
    __syncthreads();

#pragma unroll
    for (int ks = 0; ks < 2; ++ks) {
      short8 af[4], bf[4];
#pragma unroll
      for (int i = 0; i < 4; ++i) {
        int m = wm + i * 16 + l16;
        af[i] = *(const short8*)(As + m * 64 + (((ks * 4 + quad) ^ (m & 7)) * 8));
        int n = wn + i * 16 + l16;
        bf[i] = *(const short8*)(Bs + n * 64 + (((ks * 4 + quad) ^ (n & 7)) * 8));
      }
#pragma unroll
      for (int i = 0; i < 4; ++i)
#pragma unroll
        for (int j = 0; j < 4; ++j)
          acc[i][j] = __builtin_amdgcn_mfma_f32_16x16x32_bf16(af[i], bf[j], acc[i][j], 0, 0, 0);
    }
    __syncthreads();
  }

#pragma unroll
  for (int i = 0; i < 4; ++i)
#pragma unroll
    for (int j = 0; j < 4; ++j)
#pragma unroll
      for (int r = 0; r < 4; ++r) {
        int row = bm + wm + i * 16 + quad * 4 + r;
        int col = bn + wn + j * 16 + l16;
        if (OM == 0) ((ushort_t*)Cp)[(long)row * N + col] = f2bf(acc[i][j][r]);
        else         ((float*)Cp)[(long)row * N + col]    = acc[i][j][r];
      }
}

// ---------- V transpose pre-pass: Vtg[b][kvh][hd][l] ----------

__global__ __launch_bounds__(256)
void transpose_v(const ushort_t* __restrict__ QKV, ushort_t* __restrict__ Vtg) {
  __shared__ ushort_t t[64 * 72];
  const int tid = threadIdx.x;
  const int b = blockIdx.z, kvh = blockIdx.y, l0 = blockIdx.x * 64;
#pragma unroll
  for (int r = 0; r < 2; ++r) {
    int idx = tid + r * 256;
    int row = idx >> 3, sub = idx & 7;
    short8 v = *(const short8*)(QKV + (long)(b * 2048 + l0 + row) * 3072 + 2560 + kvh * 64 + sub * 8);
    *(short8*)(t + row * 72 + sub * 8) = v;
  }
  __syncthreads();
#pragma unroll
  for (int r = 0; r < 2; ++r) {
    int idx = tid + r * 256;
    int hd = idx >> 3, sub = idx & 7;
    short8 o;
#pragma unroll
    for (int e = 0; e < 8; ++e) o[e] = (short)t[(sub * 8 + e) * 72 + hd];
    *(short8*)(Vtg + (long)((b * 8 + kvh) * 64 + hd) * 2048 + l0 + sub * 8) = o;
  }
}

// ---------- fused flash attention, S^T form, q-tile 256, 512 threads ----------
// 8 waves x 32 q/wave: 16 waves/CU resident (4/SIMD, 2x R6) to fill latency
// stalls; grid 512 = exactly 2 blocks/CU, no ragged tail. Pt stride 68
// (136B) keeps bank conflicts at 0 (R6-verified). Row-sums via ones-column
// MFMA. Staging: each wave stages 1 Ks chunk + 1 Vt chunk per iter.

__global__ __launch_bounds__(512, 4)
void attn_kernel(const ushort_t* __restrict__ QKV, const ushort_t* __restrict__ Vtg,
                 ushort_t* __restrict__ AO) {
  __shared__ ushort_t Ks[2][64 * 64];   // 16 KB dbuf [l][hd]
  __shared__ ushort_t Vt[2][64 * 64];   // 16 KB dbuf [hd][l]
  __shared__ ushort_t Pt[256 * 68];     // 34 KB [q][l], stride 68, per-wave rows

  const int tid  = threadIdx.x;
  const int wave = tid >> 6, lane = tid & 63;
  const int quad = lane >> 4, l16 = lane & 15;
  const int b = blockIdx.z, h = blockIdx.y;
  const int q0 = blockIdx.x * 256;
  const int kvh = h >> 2;
  const long tok0 = (long)b * 2048 + q0;

  // Q B-frags, loop-invariant (wq carries 0.125*log2(e) -> exp2 domain)
  short8 qf[2][2];
#pragma unroll
  for (int kb = 0; kb < 2; ++kb)
#pragma unroll
    for (int j = 0; j < 2; ++j)
      qf[kb][j] = *(const short8*)(QKV + (tok0 + wave * 32 + j * 16 + l16) * 3072
                                   + h * 64 + kb * 32 + quad * 8);

  floatx4 oacc[2][4] = {};
  floatx4 osum[2] = {};

  short8 bones;
#pragma unroll
  for (int e = 0; e < 8; ++e) bones[e] = (short)0x3F80;   // bf16 1.0

  const int lr = lane >> 3, sub = lane & 7;
  const int g = sub ^ lr;               // row&7 == lr
  const ushort_t* Kbase = QKV + (long)b * 2048 * 3072 + 2048 + kvh * 64;
  const ushort_t* Vbase = Vtg + (long)(b * 8 + kvh) * 64 * 2048;

  auto stage = [&](int bf_, int l0) {
    int row = wave * 8 + lr;            // chunk == wave (8 chunks, 8 waves)
    gld16(Kbase + (long)(l0 + row) * 3072 + g * 8, Ks[bf_] + wave * 512 + lane * 8);
    gld16(Vbase + (long)row * 2048 + l0 + g * 8, Vt[bf_] + wave * 512 + lane * 8);
  };

  stage(0, 0);

  for (int it = 0; it < 32; ++it) {
    __syncthreads();
    if (it + 1 < 32) stage((it + 1) & 1, (it + 1) * 64);
    const ushort_t* Kc = Ks[it & 1];
    const ushort_t* Vc = Vt[it & 1];

    // S^T = K . Q^T : 64 l-rows x 32 q-cols per wave
    floatx4 s[4][2] = {};
#pragma unroll
    for (int kb = 0; kb < 2; ++kb) {
      short8 kf[4];
#pragma unroll
      for (int i = 0; i < 4; ++i)
        kf[i] = *(const short8*)(Kc + (i * 16 + l16) * 64 + (((kb * 4 + quad) ^ (l16 & 7)) * 8));
#pragma unroll
      for (int i = 0; i < 4; ++i)
#pragma unroll
        for (int j = 0; j < 2; ++j)
          s[i][j] = __builtin_amdgcn_mfma_f32_16x16x32_bf16(kf[i], qf[kb][j], s[i][j], 0, 0, 0);
    }

    // p = 2^s, truncation-pack via v_perm, b64 Pt writes
#pragma unroll
    for (int i = 0; i < 4; ++i)
#pragma unroll
      for (int j = 0; j < 2; ++j) {
        float p0 = __builtin_amdgcn_exp2f(s[i][j][0]);
        float p1 = __builtin_amdgcn_exp2f(s[i][j][1]);
        float p2 = __builtin_amdgcn_exp2f(s[i][j][2]);
        float p3 = __builtin_amdgcn_exp2f(s[i][j][3]);
        uint2 w;
        w.x = __builtin_amdgcn_perm(__builtin_bit_cast(unsigned int, p1),
                                    __builtin_bit_cast(unsigned int, p0), 0x07060302u);
        w.y = __builtin_amdgcn_perm(__builtin_bit_cast(unsigned int, p3),
                                    __builtin_bit_cast(unsigned int, p2), 0x07060302u);
        int q = wave * 32 + j * 16 + l16;
        int idx = q * 68 + (((i * 2 + (quad >> 1)) ^ (l16 & 7)) * 8) + (quad & 1) * 4;
        *(uint2*)(Pt + idx) = w;
      }
    // no barrier: each wave reads only Pt rows it wrote

    // O += P . V ; row-sums += P . ones
#pragma unroll
    for (int kb = 0; kb < 2; ++kb) {
      short8 pf[2], vf[4];
#pragma unroll
      for (int im = 0; im < 2; ++im)
        pf[im] = *(const short8*)(Pt + (wave * 32 + im * 16 + l16) * 68
                                  + (((kb * 4 + quad) ^ (l16 & 7)) * 8));
#pragma unroll
      for (int n = 0; n < 4; ++n)
        vf[n] = *(const short8*)(Vc + (n * 16 + l16) * 64
                                 + (((kb * 4 + quad) ^ (l16 & 7)) * 8));
#pragma unroll
      for (int im = 0; im < 2; ++im) {
#pragma unroll
        for (int n = 0; n < 4; ++n)
          oacc[im][n] = __builtin_amdgcn_mfma_f32_16x16x32_bf16(pf[im], vf[n], oacc[im][n], 0, 0, 0);
        osum[im] = __builtin_amdgcn_mfma_f32_16x16x32_bf16(pf[im], bones, osum[im], 0, 0, 0);
      }
    }
  }

  // epilogue: osum[im][r] is the softmax denominator, same layout as oacc.
#pragma unroll
  for (int im = 0; im < 2; ++im) {
    floatx4 inv;
#pragma unroll
    for (int r = 0; r < 4; ++r) inv[r] = 1.0f / osum[im][r];
#pragma unroll
    for (int n = 0; n < 4; ++n)
#pragma unroll
      for (int r = 0; r < 4; ++r) {
        long t = tok0 + wave * 32 + im * 16 + quad * 4 + r;
        AO[t * 2048 + h * 64 + n * 16 + l16] = f2bf(oacc[im][n][r] * inv[r]);
      }
  }
}

// ---------- launch ----------

extern "C" void kernel_launch(void* const* d_in, const int* in_sizes, int n_in,
                              void* d_out, int out_size, void* d_ws, size_t ws_size,
                              hipStream_t stream) {
  const float* h  = (const float*)d_in[0];
  const float* wq = (const float*)d_in[1];
  const float* wk = (const float*)d_in[2];
  const float* wv = (const float*)d_in[3];
  const float* wo = (const float*)d_in[4];
  float* out = (float*)d_out;

  const int BS = 4096, D = 2048, KV = 512, NQKV = 3072;

  ushort_t* h_bf    = (ushort_t*)d_ws;
  ushort_t* wqkv_bf = h_bf + (long)BS * D;
  ushort_t* wo_bf   = wqkv_bf + (long)NQKV * D;
  ushort_t* QKV     = wo_bf + (long)D * D;
  ushort_t* Vtg     = QKV + (long)BS * NQKV;
  ushort_t* AO      = h_bf;   // reuse: h_bf dead after QKV gemm

  const float qscale = 0.125f * 1.44269504088896f;  // 1/sqrt(64) * log2(e)

  cast_all_kernel<<<4718592 / 256, 256, 0, stream>>>(h, wq, wk, wv, wo,
                                                     h_bf, wqkv_bf, wo_bf, qscale);

  gemm_bt<0><<<dim3(BS / 128, NQKV / 128), 256, 0, stream>>>(h_bf, wqkv_bf, QKV, BS, NQKV, D);

  transpose_v<<<dim3(32, 8, 2), 256, 0, stream>>>(QKV, Vtg);

  attn_kernel<<<dim3(2048 / 256, 32, 2), 512, 0, stream>>>(QKV, Vtg, AO);

  gemm_bt<1><<<dim3(BS / 128, D / 128), 256, 0, stream>>>(AO, wo_bf, out, BS, D, D);
}